// Round 4
// baseline (415.976 us; speedup 1.0000x reference)
//
#include <hip/hip_runtime.h>
#include <math.h>

typedef unsigned short u16;
typedef __bf16 bf16x8 __attribute__((ext_vector_type(8)));
typedef float f32x4 __attribute__((ext_vector_type(4)));
typedef short s16x8 __attribute__((ext_vector_type(8)));
typedef short s16x4 __attribute__((ext_vector_type(4)));

__device__ __forceinline__ float b2f(u16 u) {
    union { unsigned i; float f; } c; c.i = ((unsigned)u) << 16; return c.f;
}
__device__ __forceinline__ u16 f2b(float f) {
    union { float f; unsigned i; } c; c.f = f;
    return (u16)((c.i + 0x7fffu + ((c.i >> 16) & 1u)) >> 16);
}
__device__ __forceinline__ float gelu_f(float v) {
    return 0.5f * v * (1.0f + erff(v * 0.70710678118654752f));
}
__device__ __forceinline__ void async_cp16(const u16* g, u16* l) {
    __builtin_amdgcn_global_load_lds((const __attribute__((address_space(1))) void*)g,
                                     (__attribute__((address_space(3))) void*)l, 16, 0, 0);
}

// C[m][colh] = sum_k A[m][k]*W[colh][k] + bias[colh]; A/W bf16, bias f32.
// Block = 32 rows x (256*SUBN) cols; 4 waves side-by-side in cols (wave tile 32x64*SUBN).
// K-loop: BK=32, single-buffered, plain __syncthreads. Small LDS (36KB @SUBN=2)
// + 32-row tiles -> 1024-block grids -> 4 blocks/CU: latency hidden by block TLP.
// mode 0: bf16 store. mode 1: f32 sigmoid store.
// mode 2: LN(g,b) -> bf16. mode 3: gelu(LN) -> bf16. mode 4: gelu(LN) -> f32 + attn ones.
// LN modes require halfBlocks==1 (block spans the whole LN group).
template<int SUBN>
__global__ __launch_bounds__(256, 4)
void gemm_bt(const u16* __restrict__ A0, const u16* __restrict__ A1,
             const u16* __restrict__ W0, const u16* __restrict__ W1,
             const float* __restrict__ B0, const float* __restrict__ B1,
             const float* __restrict__ LG0, const float* __restrict__ LB0,
             const float* __restrict__ LG1, const float* __restrict__ LB1,
             void* __restrict__ O0v, void* __restrict__ O1v,
             int lda, int K, int halfBlocks, int ldo0, int ldo1,
             int mode0, int mode1)
{
    constexpr int NCOL = 256 * SUBN;       // block cols
    constexpr int WCH  = NCOL / 64;        // W chunks per thread per K-step (8 or 4)
    __shared__ u16 sA[32 * 32];            // 2 KB
    __shared__ u16 sW[NCOL * 32];          // 32 KB (SUBN=2) / 16 KB
    __shared__ float sp[4][32][2];         // per-wave LN partials (s, ss)
    __shared__ float mrs[32][2];           // per-row (mean, rsqrt)

    const int bx = blockIdx.x, by = blockIdx.y;
    const int half = (bx >= halfBlocks) ? 1 : 0;
    const int bxl = bx - half * halfBlocks;
    const u16* A = (half ? A1 : A0) + (size_t)by * 32 * lda;
    const u16* W = (half ? W1 : W0) + (size_t)bxl * NCOL * K;
    const float* bias = half ? B1 : B0;
    const float* lng = half ? LG1 : LG0;
    const float* lnb = half ? LB1 : LB0;
    void* outv = half ? O1v : O0v;
    const int ldo = half ? ldo1 : ldo0;
    const int mode = half ? mode1 : mode0;

    const int tid = threadIdx.x;
    const int lane = tid & 63;
    const int wave = tid >> 6;   // 0..3 -> column group
    const int fc = lane & 15;
    const int quad = lane >> 4;

    // BK=32 row-pair swizzle: (r, c8) <-> slot s:
    //   s = (r>>1)*8 + (((r&1)*4 + c8 + (r>>1)) & 7)
    // bijective per 8-slot group; fragment reads land 2 lanes per 4-bank group
    // (wave64 minimum) -> conflict-free (verified: 0 bank conflicts r2/r3).
    // Stage-side inverse: p -> (r, c8): hi=p>>3, t7=((p&7)-hi)&7, r=2*hi+(t7>>2), c8=t7&3.
    int arw, ac8;   // valid for tid<128 (A tile is 32x32 = 128 chunks)
    { const int hi = tid >> 3, t7 = ((tid & 7) - hi) & 7; arw = (hi << 1) + (t7 >> 2); ac8 = t7 & 3; }
    int wrw[WCH], wc8[WCH];
#pragma unroll
    for (int c = 0; c < WCH; ++c) {
        const int p = tid + 256 * c;
        const int hi = p >> 3, t7 = ((p & 7) - hi) & 7;
        wrw[c] = (hi << 1) + (t7 >> 2); wc8[c] = t7 & 3;
    }

    // K-step-invariant fragment offsets (u16 index)
    int aoff[2];
#pragma unroll
    for (int i = 0; i < 2; ++i) {
        const int ar = i * 16 + fc;
        const int s = ((ar >> 1) << 3) + ((((ar & 1) << 2) + quad + (ar >> 1)) & 7);
        aoff[i] = s * 8;
    }
    int woff[4 * SUBN];
#pragma unroll
    for (int sub = 0; sub < SUBN; ++sub)
#pragma unroll
    for (int j = 0; j < 4; ++j) {
        const int wr = wave * (64 * SUBN) + sub * 64 + j * 16 + fc;
        const int s = ((wr >> 1) << 3) + ((((wr & 1) << 2) + quad + (wr >> 1)) & 7);
        woff[sub * 4 + j] = s * 8;
    }

    f32x4 acc[2][4 * SUBN];
#pragma unroll
    for (int i = 0; i < 2; ++i)
#pragma unroll
        for (int j = 0; j < 4 * SUBN; ++j)
            acc[i][j] = f32x4{0.f, 0.f, 0.f, 0.f};

    const int NT = K >> 5;
    for (int t = 0; t < NT; ++t) {
        const int k0 = t << 5;
        if (tid < 128)
            async_cp16(A + (size_t)arw * lda + k0 + ac8 * 8, &sA[tid * 8]);
#pragma unroll
        for (int c = 0; c < WCH; ++c)
            async_cp16(W + (size_t)wrw[c] * K + k0 + wc8[c] * 8,
                       &sW[(tid + 256 * c) * 8]);
        __syncthreads();               // drains vmcnt(0): tile ready

        bf16x8 af[2];
#pragma unroll
        for (int i = 0; i < 2; ++i) af[i] = *(const bf16x8*)&sA[aoff[i]];
#pragma unroll
        for (int sub = 0; sub < SUBN; ++sub) {
            bf16x8 wf[4];
#pragma unroll
            for (int j = 0; j < 4; ++j) wf[j] = *(const bf16x8*)&sW[woff[sub * 4 + j]];
#pragma unroll
            for (int i = 0; i < 2; ++i)
#pragma unroll
            for (int j = 0; j < 4; ++j)
                acc[i][sub * 4 + j] =
                    __builtin_amdgcn_mfma_f32_16x16x32_bf16(af[i], wf[j], acc[i][sub * 4 + j], 0, 0, 0);
        }
        __syncthreads();               // all reads done before next overwrite
    }

    const int colb = bxl * NCOL;

    if (mode <= 1) {
        // direct stores (mode 0 bf16, mode 1 sigmoid f32)
#pragma unroll
        for (int sub = 0; sub < SUBN; ++sub)
#pragma unroll
        for (int j = 0; j < 4; ++j) {
            const int colh = colb + wave * 64 * SUBN + sub * 64 + j * 16 + fc;
            const float bv = bias[colh];
#pragma unroll
            for (int i = 0; i < 2; ++i)
#pragma unroll
            for (int r = 0; r < 4; ++r) {
                const int row = by * 32 + i * 16 + quad * 4 + r;
                const float v = acc[i][sub * 4 + j][r] + bv;
                if (mode == 1)
                    ((float*)outv)[(size_t)row * ldo + colh] = 1.0f / (1.0f + expf(-v));
                else
                    ((u16*)outv)[(size_t)row * ldo + colh] = f2b(v);
            }
        }
    } else {
        // Fused LN epilogue, register-resident (halfBlocks==1 -> colb==0).
        // Phase 0: fold bias into acc (f32).
        float gvv[SUBN * 4], bvv[SUBN * 4];
#pragma unroll
        for (int sub = 0; sub < SUBN; ++sub)
#pragma unroll
        for (int j = 0; j < 4; ++j) {
            const int feat = wave * 64 * SUBN + sub * 64 + j * 16 + fc;
            const float bv = bias[feat];
            gvv[sub * 4 + j] = lng[feat];
            bvv[sub * 4 + j] = lnb[feat];
#pragma unroll
            for (int i = 0; i < 2; ++i)
#pragma unroll
            for (int r = 0; r < 4; ++r)
                acc[i][sub * 4 + j][r] += bv;
        }
        // Phase 1: per-(row) partial sums over this wave's 64*SUBN cols,
        // reduced across the 16 fc-lanes (quad preserved -> row preserved).
#pragma unroll
        for (int i = 0; i < 2; ++i)
#pragma unroll
        for (int r = 0; r < 4; ++r) {
            float s = 0.f, ss = 0.f;
#pragma unroll
            for (int sj = 0; sj < SUBN * 4; ++sj) {
                const float v = acc[i][sj][r];
                s += v; ss += v * v;
            }
#pragma unroll
            for (int m = 1; m <= 8; m <<= 1) {
                s += __shfl_xor(s, m, 64);
                ss += __shfl_xor(ss, m, 64);
            }
            if (fc == 0) {
                const int rl = i * 16 + quad * 4 + r;
                sp[wave][rl][0] = s;
                sp[wave][rl][1] = ss;
            }
        }
        __syncthreads();
        // Phase 2: totals + mean/rsqrt per row
        constexpr float INV = 1.0f / (float)NCOL;
        if (tid < 32) {
            const float s  = sp[0][tid][0] + sp[1][tid][0] + sp[2][tid][0] + sp[3][tid][0];
            const float ss = sp[0][tid][1] + sp[1][tid][1] + sp[2][tid][1] + sp[3][tid][1];
            const float mean = s * INV;
            const float var = ss * INV - mean * mean;
            mrs[tid][0] = mean;
            mrs[tid][1] = rsqrtf(var + 1e-5f);
        }
        __syncthreads();
        // Phase 3: normalize registers + store
#pragma unroll
        for (int i = 0; i < 2; ++i)
#pragma unroll
        for (int r = 0; r < 4; ++r) {
            const int rl = i * 16 + quad * 4 + r;
            const int grow = by * 32 + rl;
            const float mean = mrs[rl][0], rs = mrs[rl][1];
#pragma unroll
            for (int sub = 0; sub < SUBN; ++sub)
#pragma unroll
            for (int j = 0; j < 4; ++j) {
                const int feat = wave * 64 * SUBN + sub * 64 + j * 16 + fc;
                float y = (acc[i][sub * 4 + j][r] - mean) * rs * gvv[sub * 4 + j] + bvv[sub * 4 + j];
                if (mode >= 3) y = gelu_f(y);
                if (mode == 4)
                    ((float*)outv)[(size_t)grow * ldo + feat] = y;
                else
                    ((u16*)outv)[(size_t)grow * ldo + feat] = f2b(y);
            }
        }
        if (mode == 4 && tid < 32) {
            float* o = (float*)outv;
            o[(size_t)16384 * 768 + by * 32 + tid] = 1.0f;   // attn_n2t
            o[(size_t)16384 * 769 + by * 32 + tid] = 1.0f;   // attn_t2n
        }
    }
}

// ---- prep ---------------------------------------------------------------

__device__ __forceinline__ void cvt_quads(const float* __restrict__ src,
                                          u16* __restrict__ dst, int bi, int tid)
{
#pragma unroll
    for (int c = 0; c < 2; ++c) {
        const int q = bi * 512 + tid + 256 * c;
        f32x4 v = *(const f32x4*)(src + (size_t)q * 4);
        s16x4 o;
        o[0] = (short)f2b(v[0]); o[1] = (short)f2b(v[1]);
        o[2] = (short)f2b(v[2]); o[3] = (short)f2b(v[3]);
        *(s16x4*)(dst + (size_t)q * 4) = o;
    }
}

// one 64x64 tile transpose+cvt: dst[(tc+j)*R + tr+i] = src[(tr+i)*C + tc+j]
__device__ void transpose_cvt64(const float* __restrict__ src, int C,
                                u16* __restrict__ dst, int R,
                                int tr, int tc, int tid, float* sm)
{
    const int lr = tid >> 4, lc4 = (tid & 15) * 4;
#pragma unroll
    for (int m = 0; m < 4; ++m) {
        const int i = lr + m * 16;
        f32x4 v = *(const f32x4*)&src[(size_t)(tr + i) * C + tc + lc4];
#pragma unroll
        for (int mm = 0; mm < 4; ++mm) sm[i * 65 + lc4 + mm] = v[mm];
    }
    __syncthreads();
#pragma unroll
    for (int m = 0; m < 4; ++m) {
        const int j = lr + m * 16;
        s16x4 o;
#pragma unroll
        for (int mm = 0; mm < 4; ++mm)
            o[mm] = (short)f2b(sm[(size_t)(lc4 + mm) * 65 + j]);
        *(s16x4*)&dst[(size_t)(tc + j) * R + tr + lc4] = o;
    }
}

// wv[i] = sum_k M[i][k]*v[k] + add1[i] + add2[i]  (M f32 [512x512]); 64 rows/block
__device__ void matvec_rows(const float* __restrict__ M, const float* __restrict__ v,
                            const float* __restrict__ add1, const float* __restrict__ add2,
                            float* __restrict__ out, int r0, int tid, float* sm)
{
    for (int i = tid; i < 512; i += 256) sm[i] = v[i];
    __syncthreads();
    const int row = r0 + (tid & 63), q = tid >> 6;
    float s = 0.f;
    for (int k = q * 128; k < q * 128 + 128; k += 4) {
        f32x4 m = *(const f32x4*)&M[(size_t)row * 512 + k];
        s += m[0] * sm[k] + m[1] * sm[k + 1] + m[2] * sm[k + 2] + m[3] * sm[k + 3];
    }
    sm[512 + tid] = s;
    __syncthreads();
    if (tid < 64)
        out[r0 + tid] = sm[512 + tid] + sm[512 + tid + 64] + sm[512 + tid + 128] +
                        sm[512 + tid + 192] + add1[r0 + tid] + add2[r0 + tid];
}

// prep_cvt: EMB cvt, weight cvts, transposes, w1/w2, zbias. All memory-bound.
__global__ __launch_bounds__(256)
void prep_cvt(const float* __restrict__ text, const float* __restrict__ num,
              const float* __restrict__ tp_w, const float* __restrict__ np_w,
              const float* __restrict__ g_w, const float* __restrict__ m1_w,
              const float* __restrict__ m2_w,
              const float* __restrict__ a1_wv, const float* __restrict__ a2_wv,
              const float* __restrict__ a1_wo, const float* __restrict__ a2_wo,
              const float* __restrict__ a1_bv, const float* __restrict__ a1_bo,
              const float* __restrict__ a2_bv, const float* __restrict__ a2_bo,
              const float* __restrict__ tp_b, const float* __restrict__ np_b,
              u16* __restrict__ EMBc, u16* __restrict__ Wbig,
              u16* __restrict__ g_bf, u16* __restrict__ m1_bf, u16* __restrict__ m2_bf,
              u16* __restrict__ a1_wvT, u16* __restrict__ a2_wvT,
              u16* __restrict__ tp_wT, u16* __restrict__ np_wT,
              u16* __restrict__ a1_wo_bf, u16* __restrict__ a2_wo_bf,
              float* __restrict__ w1, float* __restrict__ w2,
              float* __restrict__ zb)
{
    __shared__ float smem[64 * 65];
    const int b = blockIdx.x, tid = threadIdx.x;
    if (b < 4096) {                       // EMBc[row,0:256]=text, [256:512]=num
#pragma unroll
        for (int c = 0; c < 2; ++c) {
            const int q = b * 512 + tid + 256 * c;
            const int e = q * 4, row = e >> 9, col = e & 511;
            const float* src = (col < 256) ? text + (size_t)row * 256 + col
                                           : num + (size_t)row * 256 + (col - 256);
            f32x4 v = *(const f32x4*)src;
            s16x4 o;
            o[0] = (short)f2b(v[0]); o[1] = (short)f2b(v[1]);
            o[2] = (short)f2b(v[2]); o[3] = (short)f2b(v[3]);
            *(s16x4*)(EMBc + e) = o;
        }
    } else if (b < 4352) { cvt_quads(g_w, g_bf, b - 4096, tid); }
    else if (b < 4608) { cvt_quads(m1_w, m1_bf, b - 4352, tid); }
    else if (b < 4672) { cvt_quads(m2_w, m2_bf, b - 4608, tid); }
    else if (b < 4736) {                  // np_w -> Wbig[0:512, 256:512]
#pragma unroll
        for (int c = 0; c < 2; ++c) {
            const int q = (b - 4672) * 512 + tid + 256 * c;
            const int e = q * 4, row = e >> 8, col = e & 255;
            f32x4 v = *(const f32x4*)(np_w + e);
            s16x4 o;
            o[0] = (short)f2b(v[0]); o[1] = (short)f2b(v[1]);
            o[2] = (short)f2b(v[2]); o[3] = (short)f2b(v[3]);
            *(s16x4*)(Wbig + (size_t)row * 512 + 256 + col) = o;
        }
    } else if (b < 4800) {                // tp_w -> Wbig[512:1024, 0:256]
#pragma unroll
        for (int c = 0; c < 2; ++c) {
            const int q = (b - 4736) * 512 + tid + 256 * c;
            const int e = q * 4, row = e >> 8, col = e & 255;
            f32x4 v = *(const f32x4*)(tp_w + e);
            s16x4 o;
            o[0] = (short)f2b(v[0]); o[1] = (short)f2b(v[1]);
            o[2] = (short)f2b(v[2]); o[3] = (short)f2b(v[3]);
            *(s16x4*)(Wbig + (size_t)(512 + row) * 512 + col) = o;
        }
    } else if (b < 4864) {                // a1_wvT = a1_wv.T (bf16)
        const int t = b - 4800;
        transpose_cvt64(a1_wv, 512, a1_wvT, 512, (t >> 3) * 64, (t & 7) * 64, tid, smem);
    } else if (b < 4928) {
        const int t = b - 4864;
        transpose_cvt64(a2_wv, 512, a2_wvT, 512, (t >> 3) * 64, (t & 7) * 64, tid, smem);
    } else if (b < 4960) {                // tp_wT [256x512]
        const int t = b - 4928;
        transpose_cvt64(tp_w, 256, tp_wT, 512, (t >> 2) * 64, (t & 3) * 64, tid, smem);
    } else if (b < 4992) {                // np_wT [256x512]
        const int t = b - 4960;
        transpose_cvt64(np_w, 256, np_wT, 512, (t >> 2) * 64, (t & 3) * 64, tid, smem);
    } else if (b < 5120) { cvt_quads(a1_wo, a1_wo_bf, b - 4992, tid); }
    else if (b < 5248) { cvt_quads(a2_wo, a2_wo_bf, b - 5120, tid); }
    else if (b < 5256) {                  // w1 = a1_wo@a1_bv + a1_bo + np_b
        matvec_rows(a1_wo, a1_bv, a1_bo, np_b, w1, (b - 5248) * 64, tid, smem);
    } else if (b < 5264) {                // w2 = a2_wo@a2_bv + a2_bo + tp_b
        matvec_rows(a2_wo, a2_bv, a2_bo, tp_b, w2, (b - 5256) * 64, tid, smem);
    } else {                              // zb[1024] = 0
        *(f32x4*)&zb[tid * 4] = f32x4{0.f, 0.f, 0.f, 0.f};
    }
}

// bbig[0:512] = M1@tp_b + w1 ; bbig[512:1024] = M2@np_b + w2. M bf16 [512x512].
__global__ __launch_bounds__(256)
void prep_bias(const u16* __restrict__ M1, const u16* __restrict__ M2,
               const float* __restrict__ tp_b, const float* __restrict__ np_b,
               const float* __restrict__ w1, const float* __restrict__ w2,
               float* __restrict__ bbig)
{
    __shared__ float sm[768];
    const int b = blockIdx.x, tid = threadIdx.x;
    const int side = b >> 3, r0 = (b & 7) * 64;
    const u16* M = side ? M2 : M1;
    const float* v = side ? np_b : tp_b;
    const float* w = side ? w2 : w1;
    float* out = bbig + side * 512;
    for (int i = tid; i < 512; i += 256) sm[i] = v[i];
    __syncthreads();
    const int row = r0 + (tid & 63), q = tid >> 6;
    float s = 0.f;
    for (int k = q * 128; k < q * 128 + 128; k += 8) {
        s16x8 m = *(const s16x8*)&M[(size_t)row * 512 + k];
#pragma unroll
        for (int j = 0; j < 8; ++j) s += b2f((u16)m[j]) * sm[k + j];
    }
    sm[512 + tid] = s;
    __syncthreads();
    if (tid < 64)
        out[r0 + tid] = sm[512 + tid] + sm[512 + tid + 64] + sm[512 + tid + 128] +
                        sm[512 + tid + 192] + w[r0 + tid];
}

extern "C" void kernel_launch(void* const* d_in, const int* in_sizes, int n_in,
                              void* d_out, int out_size, void* d_ws, size_t ws_size,
                              hipStream_t stream)
{
    const float* text  = (const float*)d_in[0];
    const float* num   = (const float*)d_in[1];
    const float* tp_w  = (const float*)d_in[2];
    const float* tp_b  = (const float*)d_in[3];
    const float* np_w  = (const float*)d_in[4];
    const float* np_b  = (const float*)d_in[5];
    const float* a1_wv = (const float*)d_in[8];
    const float* a1_bv = (const float*)d_in[11];
    const float* a1_wo = (const float*)d_in[12];
    const float* a1_bo = (const float*)d_in[13];
    const float* a2_wv = (const float*)d_in[16];
    const float* a2_bv = (const float*)d_in[19];
    const float* a2_wo = (const float*)d_in[20];
    const float* a2_bo = (const float*)d_in[21];
    const float* n1_g  = (const float*)d_in[22];
    const float* n1_b  = (const float*)d_in[23];
    const float* n2_g  = (const float*)d_in[24];
    const float* n2_b  = (const float*)d_in[25];
    const float* g_w   = (const float*)d_in[26];
    const float* g_b   = (const float*)d_in[27];
    const float* m1_w  = (const float*)d_in[28];
    const float* m1_b  = (const float*)d_in[29];
    const float* ln1_g = (const float*)d_in[30];
    const float* ln1_b = (const float*)d_in[31];
    const float* m2_w  = (const float*)d_in[32];
    const float* m2_b  = (const float*)d_in[33];
    const float* ln2_g = (const float*)d_in[34];
    const float* ln2_b = (const float*)d_in[35];

    float* outp = (float*)d_out;
    char* ob = (char*)d_out;
    char* ws = (char*)d_ws;
    const size_t KB = 1024, MB = 1048576;

    // d_out scratch: [0,16MB) dead until G3; [16,48MB) dead until G2 (EMBc)
    u16* Wbig    = (u16*)(ob);                       // 1 MB   [1024x512]
    u16* g_bf    = (u16*)(ob + 1 * MB);              // 1 MB   [512x1024]
    u16* m1_bf   = (u16*)(ob + 2 * MB);              // 1 MB   [512x1024]
    u16* a1_wvT  = (u16*)(ob + 3 * MB + 256 * KB);   // 512 KB [512x512]
    u16* a2_wvT  = (u16*)(ob + 3 * MB + 768 * KB);   // 512 KB
    u16* tp_wT   = (u16*)(ob + 4 * MB + 256 * KB);   // 256 KB [256x512]
    u16* np_wT   = (u16*)(ob + 4 * MB + 512 * KB);   // 256 KB
    u16* a1_wo_bf= (u16*)(ob + 4 * MB + 768 * KB);   // 512 KB [512x512]
    u16* a2_wo_bf= (u16*)(ob + 5 * MB + 256 * KB);   // 512 KB
    u16* M1      = (u16*)(ob + 5 * MB + 768 * KB);   // 512 KB [512x512]
    u16* M2      = (u16*)(ob + 6 * MB + 256 * KB);   // 512 KB
    float* w1    = (float*)(ob + 6 * MB + 768 * KB); // 2 KB
    float* w2    = w1 + 512;                         // 2 KB
    float* bbig  = w1 + 1024;                        // 4 KB
    float* zb    = w1 + 2048;                        // 4 KB
    u16* EMBc    = (u16*)(ob + 16 * MB);             // 16 MB [16384x512]
    // ws: X live prep->G2; m2_bf live prep->G3 (kept out of d_out[0,16MB) since
    // fused G3 writes d_out[0,16MB) while reading m2_bf); h live G2->G3.
    u16* X     = (u16*)ws;                           // 32 MB [16384x1024]
    u16* m2_bf = (u16*)(ws + 32 * MB);               // 256 KB [256x512]
    u16* h     = (u16*)(ws + 48 * MB);               // 16 MB [16384x512]

    dim3 blk(256);

    // P1: conversions, transposes, w1/w2, zbias
    prep_cvt<<<5265, blk, 0, stream>>>(text, num, tp_w, np_w, g_w, m1_w, m2_w,
        a1_wv, a2_wv, a1_wo, a2_wo, a1_bv, a1_bo, a2_bv, a2_bo, tp_b, np_b,
        EMBc, Wbig, g_bf, m1_bf, m2_bf, a1_wvT, a2_wvT, tp_wT, np_wT,
        a1_wo_bf, a2_wo_bf, w1, w2, zb);
    // F1: M1 = a1_wo@a1_wv ; M2 = a2_wo@a2_wv   (MFMA, bf16 out)
    gemm_bt<2><<<dim3(2, 16), blk, 0, stream>>>(a1_wo_bf, a2_wo_bf, a1_wvT, a2_wvT,
        zb, zb, nullptr, nullptr, nullptr, nullptr,
        M1, M2, 512, 512, 1, 512, 512, 0, 0);
    // PB: bbig = [M1@tp_b + w1 | M2@np_b + w2]
    prep_bias<<<16, blk, 0, stream>>>(M1, M2, tp_b, np_b, w1, w2, bbig);
    // F2: Wbig[0:512,0:256] = M1@tp_w ; Wbig[512:,256:] = M2@np_w
    gemm_bt<1><<<dim3(2, 16), blk, 0, stream>>>(M1, M2, tp_wT, np_wT,
        zb, zb, nullptr, nullptr, nullptr, nullptr,
        Wbig, Wbig + (size_t)512 * 512 + 256, 512, 512, 1, 512, 512, 0, 0);
    // G1+L1: X = LN(EMBc @ Wbig.T + bbig) per 512-col half (n1 | n2), fused
    gemm_bt<2><<<dim3(2, 512), blk, 0, stream>>>(EMBc, EMBc,
        Wbig, Wbig + (size_t)512 * 512, bbig, bbig + 512,
        n1_g, n1_b, n2_g, n2_b,
        X, X + 512, 512, 512, 1, 1024, 1024, 2, 2);
    // G2+L2: gate = sigmoid(comb@g_w.T+g_b) -> d_out f32 ; h = gelu(LN1(comb@m1_w.T+m1_b))
    gemm_bt<2><<<dim3(2, 512), blk, 0, stream>>>(X, X, g_bf, m1_bf, g_b, m1_b,
        nullptr, nullptr, ln1_g, ln1_b,
        outp + (size_t)16384 * 256, h, 1024, 1024, 1, 512, 512, 1, 3);
    // G3+L3: fused = gelu(LN2(h @ m2_w.T + m2_b)) -> d_out f32; attn = 1.0
    gemm_bt<1><<<dim3(1, 512), blk, 0, stream>>>(h, h, m2_bf, m2_bf, m2_b, m2_b,
        ln2_g, ln2_b, ln2_g, ln2_b,
        outp, outp, 512, 512, 1, 256, 256, 4, 4);
}

// Round 5
// 299.734 us; speedup vs baseline: 1.3878x; 1.3878x over previous
//
#include <hip/hip_runtime.h>
#include <math.h>

typedef unsigned short u16;
typedef __bf16 bf16x8 __attribute__((ext_vector_type(8)));
typedef float f32x4 __attribute__((ext_vector_type(4)));
typedef short s16x8 __attribute__((ext_vector_type(8)));
typedef short s16x4 __attribute__((ext_vector_type(4)));

__device__ __forceinline__ float b2f(u16 u) {
    union { unsigned i; float f; } c; c.i = ((unsigned)u) << 16; return c.f;
}
__device__ __forceinline__ u16 f2b(float f) {
    union { float f; unsigned i; } c; c.f = f;
    return (u16)((c.i + 0x7fffu + ((c.i >> 16) & 1u)) >> 16);
}
__device__ __forceinline__ float gelu_f(float v) {
    return 0.5f * v * (1.0f + erff(v * 0.70710678118654752f));
}
__device__ __forceinline__ void async_cp16(const u16* g, u16* l) {
    __builtin_amdgcn_global_load_lds((const __attribute__((address_space(1))) void*)g,
                                     (__attribute__((address_space(3))) void*)l, 16, 0, 0);
}

// C[m][colh] = sum_k A[m][k]*W[colh][k] + bias[colh]; A/W bf16, bias f32.
// Block = (IR*16) rows x (256*SUBN) cols; 4 waves side-by-side in cols.
// K-loop: BK=64, single-buffered, plain __syncthreads (best-measured structure, R1).
// IR=4 for the big fused GEMMs; IR=1 gives 16-row tiles so the tiny F1/F2
// GEMMs get 64-128 block grids (latency hidden by CU count, not per-CU TLP).
// mode 0: bf16 store. mode 1: f32 sigmoid store.
// mode 2: LN(g,b) -> bf16. mode 3: gelu(LN) -> bf16. mode 4: gelu(LN) -> f32 + attn ones.
// LN modes require halfBlocks==1 (block spans the whole LN group) and IR==4.
template<int SUBN, int IR>
__global__ __launch_bounds__(256, 2)
void gemm_bt(const u16* __restrict__ A0, const u16* __restrict__ A1,
             const u16* __restrict__ W0, const u16* __restrict__ W1,
             const float* __restrict__ B0, const float* __restrict__ B1,
             const float* __restrict__ LG0, const float* __restrict__ LB0,
             const float* __restrict__ LG1, const float* __restrict__ LB1,
             void* __restrict__ O0v, void* __restrict__ O1v,
             int lda, int K, int halfBlocks, int ldo0, int ldo1,
             int mode0, int mode1)
{
    constexpr int BM   = IR * 16;           // block rows
    constexpr int NCOL = 256 * SUBN;        // block cols
    constexpr int WCH  = 8 * SUBN;          // W chunks per thread per K-step
    constexpr int EPIW = NCOL + 8;          // padded epilogue row stride (u16)
    constexpr int STAGEU = (BM + NCOL) * 64;
    constexpr int EPIS = (IR == 4) ? 64 * EPIW : 0;
    __shared__ u16 sm[(STAGEU > EPIS) ? STAGEU : EPIS];
    u16* sA = sm;
    u16* sW = sm + BM * 64;

    const int bx = blockIdx.x, by = blockIdx.y;
    const int half = (bx >= halfBlocks) ? 1 : 0;
    const int bxl = bx - half * halfBlocks;
    const u16* A = (half ? A1 : A0) + (size_t)by * BM * lda;
    const u16* W = (half ? W1 : W0) + (size_t)bxl * NCOL * K;
    const float* bias = half ? B1 : B0;
    const float* lng = half ? LG1 : LG0;
    const float* lnb = half ? LB1 : LB0;
    void* outv = half ? O1v : O0v;
    const int ldo = half ? ldo1 : ldo0;
    const int mode = half ? mode1 : mode0;

    const int tid = threadIdx.x;
    const int lane = tid & 63;
    const int wave = tid >> 6;   // 0..3 -> column group
    const int fc = lane & 15;
    const int quad = lane >> 4;

    // chunk slot p (16B) holds row r=p>>3, logical k8-chunk c8=((p&7)-(r&7))&7;
    // i.e. physical slot for (r,c8) is r*8 + ((c8 + r)&7) -> bank-spread frag reads.
    int par[2], pac[2];
#pragma unroll
    for (int c = 0; c < 2; ++c) {
        const int p = tid + 256 * c;
        par[c] = p >> 3;
        pac[c] = ((p & 7) - (par[c] & 7)) & 7;
    }
    int pwr[WCH], pwc[WCH];
#pragma unroll
    for (int c = 0; c < WCH; ++c) {
        const int p = tid + 256 * c;
        pwr[c] = p >> 3;
        pwc[c] = ((p & 7) - (pwr[c] & 7)) & 7;
    }

    f32x4 acc[IR][4 * SUBN];
#pragma unroll
    for (int i = 0; i < IR; ++i)
#pragma unroll
        for (int j = 0; j < 4 * SUBN; ++j)
            acc[i][j] = f32x4{0.f, 0.f, 0.f, 0.f};

    for (int k0 = 0; k0 < K; k0 += 64) {
#pragma unroll
        for (int c = 0; c < 2; ++c) {
            const int p = tid + 256 * c;
            if (p < BM * 8)
                async_cp16(A + (size_t)par[c] * lda + k0 + pac[c] * 8, &sA[p * 8]);
        }
#pragma unroll
        for (int c = 0; c < WCH; ++c)
            async_cp16(W + (size_t)pwr[c] * K + k0 + pwc[c] * 8,
                       &sW[(tid + 256 * c) * 8]);
        __syncthreads();

#pragma unroll
        for (int kk = 0; kk < 2; ++kk) {
            bf16x8 af[IR];
#pragma unroll
            for (int i = 0; i < IR; ++i) {
                const int ar = i * 16 + fc;
                const int slot = ar * 8 + ((kk * 4 + quad + (ar & 7)) & 7);
                af[i] = *(const bf16x8*)&sA[slot * 8];
            }
#pragma unroll
            for (int sub = 0; sub < SUBN; ++sub) {
                bf16x8 wf[4];
#pragma unroll
                for (int j = 0; j < 4; ++j) {
                    const int wr = wave * 64 * SUBN + sub * 64 + j * 16 + fc;
                    const int slot = wr * 8 + ((kk * 4 + quad + (wr & 7)) & 7);
                    wf[j] = *(const bf16x8*)&sW[slot * 8];
                }
#pragma unroll
                for (int i = 0; i < IR; ++i)
#pragma unroll
                    for (int j = 0; j < 4; ++j)
                        acc[i][sub * 4 + j] =
                            __builtin_amdgcn_mfma_f32_16x16x32_bf16(af[i], wf[j], acc[i][sub * 4 + j], 0, 0, 0);
            }
        }
        __syncthreads();
    }

    const int colb = bxl * NCOL;

    if (mode <= 1) {
        // direct stores (mode 0 bf16, mode 1 sigmoid f32)
#pragma unroll
        for (int sub = 0; sub < SUBN; ++sub)
#pragma unroll
        for (int j = 0; j < 4; ++j) {
            const int colh = colb + wave * 64 * SUBN + sub * 64 + j * 16 + fc;
            const float bv = bias[colh];
#pragma unroll
            for (int i = 0; i < IR; ++i)
#pragma unroll
            for (int r = 0; r < 4; ++r) {
                const int row = by * BM + i * 16 + quad * 4 + r;
                const float v = acc[i][sub * 4 + j][r] + bv;
                if (mode == 1)
                    ((float*)outv)[(size_t)row * ldo + colh] = 1.0f / (1.0f + expf(-v));
                else
                    ((u16*)outv)[(size_t)row * ldo + colh] = f2b(v);
            }
        }
    } else if constexpr (IR == 4) {
        // fused LN epilogue. Phase 1: bias-add, bf16-round, scatter to padded LDS.
        // (last K-loop __syncthreads already fenced all staging reads; safe to overwrite sm)
        float bb[SUBN * 4];
#pragma unroll
        for (int sub = 0; sub < SUBN; ++sub)
#pragma unroll
        for (int j = 0; j < 4; ++j)
            bb[sub * 4 + j] = bias[colb + wave * 64 * SUBN + sub * 64 + j * 16 + fc];
#pragma unroll
        for (int sub = 0; sub < SUBN; ++sub)
#pragma unroll
        for (int j = 0; j < 4; ++j) {
            const int col = wave * 64 * SUBN + sub * 64 + j * 16 + fc;
#pragma unroll
            for (int i = 0; i < 4; ++i)
#pragma unroll
            for (int r = 0; r < 4; ++r)
                sm[(i * 16 + quad * 4 + r) * EPIW + col] =
                    f2b(acc[i][sub * 4 + j][r] + bb[sub * 4 + j]);
        }
        __syncthreads();

        // Phase 2: per-row LN (64-lane reduce, bit-identical to the old ln_* kernels)
        constexpr int CE = NCOL / 64;
        constexpr float INV = 1.0f / (float)NCOL;
        float gv[CE], bvv[CE];
#pragma unroll
        for (int e = 0; e < CE; ++e) {
            gv[e] = lng[lane * CE + e];
            bvv[e] = lnb[lane * CE + e];
        }
        for (int rr = 0; rr < 16; ++rr) {
            const int rl = wave * 16 + rr;
            const int grow = by * 64 + rl;
            float x[CE], s = 0.f, ss = 0.f;
            if constexpr (CE == 8) {
                s16x8 xv = *(const s16x8*)&sm[rl * EPIW + lane * 8];
#pragma unroll
                for (int e = 0; e < 8; ++e) { x[e] = b2f((u16)xv[e]); s += x[e]; ss += x[e] * x[e]; }
            } else {
                s16x4 xv = *(const s16x4*)&sm[rl * EPIW + lane * 4];
#pragma unroll
                for (int e = 0; e < 4; ++e) { x[e] = b2f((u16)xv[e]); s += x[e]; ss += x[e] * x[e]; }
            }
#pragma unroll
            for (int m = 32; m >= 1; m >>= 1) { s += __shfl_xor(s, m, 64); ss += __shfl_xor(ss, m, 64); }
            const float mean = s * INV;
            const float var = ss * INV - mean * mean;
            const float rs = rsqrtf(var + 1e-5f);
            float y[CE];
#pragma unroll
            for (int e = 0; e < CE; ++e) {
                y[e] = (x[e] - mean) * rs * gv[e] + bvv[e];
                if (mode >= 3) y[e] = gelu_f(y[e]);
            }
            if (mode == 4) {
                float* o = (float*)outv;
#pragma unroll
                for (int e = 0; e < CE; ++e)
                    o[(size_t)grow * ldo + colb + lane * CE + e] = y[e];
                if (lane == 0) {
                    o[(size_t)16384 * 768 + grow] = 1.0f;   // attn_n2t
                    o[(size_t)16384 * 769 + grow] = 1.0f;   // attn_t2n
                }
            } else {
                u16* o = (u16*)outv;
                if constexpr (CE == 8) {
                    s16x8 ov;
#pragma unroll
                    for (int e = 0; e < 8; ++e) ov[e] = (short)f2b(y[e]);
                    *(s16x8*)&o[(size_t)grow * ldo + colb + lane * 8] = ov;
                } else {
                    s16x4 ov;
#pragma unroll
                    for (int e = 0; e < 4; ++e) ov[e] = (short)f2b(y[e]);
                    *(s16x4*)&o[(size_t)grow * ldo + colb + lane * 4] = ov;
                }
            }
        }
    }
}

// ---- prep ---------------------------------------------------------------

__device__ __forceinline__ void cvt_quads(const float* __restrict__ src,
                                          u16* __restrict__ dst, int bi, int tid)
{
#pragma unroll
    for (int c = 0; c < 2; ++c) {
        const int q = bi * 512 + tid + 256 * c;
        f32x4 v = *(const f32x4*)(src + (size_t)q * 4);
        s16x4 o;
        o[0] = (short)f2b(v[0]); o[1] = (short)f2b(v[1]);
        o[2] = (short)f2b(v[2]); o[3] = (short)f2b(v[3]);
        *(s16x4*)(dst + (size_t)q * 4) = o;
    }
}

// one 64x64 tile transpose+cvt: dst[(tc+j)*R + tr+i] = src[(tr+i)*C + tc+j]
__device__ void transpose_cvt64(const float* __restrict__ src, int C,
                                u16* __restrict__ dst, int R,
                                int tr, int tc, int tid, float* sm)
{
    const int lr = tid >> 4, lc4 = (tid & 15) * 4;
#pragma unroll
    for (int m = 0; m < 4; ++m) {
        const int i = lr + m * 16;
        f32x4 v = *(const f32x4*)&src[(size_t)(tr + i) * C + tc + lc4];
#pragma unroll
        for (int mm = 0; mm < 4; ++mm) sm[i * 65 + lc4 + mm] = v[mm];
    }
    __syncthreads();
#pragma unroll
    for (int m = 0; m < 4; ++m) {
        const int j = lr + m * 16;
        s16x4 o;
#pragma unroll
        for (int mm = 0; mm < 4; ++mm)
            o[mm] = (short)f2b(sm[(size_t)(lc4 + mm) * 65 + j]);
        *(s16x4*)&dst[(size_t)(tc + j) * R + tr + lc4] = o;
    }
}

// wv[i] = sum_k M[i][k]*v[k] + add1[i] + add2[i]  (M f32 [512x512]); 64 rows/block
__device__ void matvec_rows(const float* __restrict__ M, const float* __restrict__ v,
                            const float* __restrict__ add1, const float* __restrict__ add2,
                            float* __restrict__ out, int r0, int tid, float* sm)
{
    for (int i = tid; i < 512; i += 256) sm[i] = v[i];
    __syncthreads();
    const int row = r0 + (tid & 63), q = tid >> 6;
    float s = 0.f;
    for (int k = q * 128; k < q * 128 + 128; k += 4) {
        f32x4 m = *(const f32x4*)&M[(size_t)row * 512 + k];
        s += m[0] * sm[k] + m[1] * sm[k + 1] + m[2] * sm[k + 2] + m[3] * sm[k + 3];
    }
    sm[512 + tid] = s;
    __syncthreads();
    if (tid < 64)
        out[r0 + tid] = sm[512 + tid] + sm[512 + tid + 64] + sm[512 + tid + 128] +
                        sm[512 + tid + 192] + add1[r0 + tid] + add2[r0 + tid];
}

// prep_cvt: EMB cvt, weight cvts, transposes, w1/w2, zbias. All memory-bound.
__global__ __launch_bounds__(256)
void prep_cvt(const float* __restrict__ text, const float* __restrict__ num,
              const float* __restrict__ tp_w, const float* __restrict__ np_w,
              const float* __restrict__ g_w, const float* __restrict__ m1_w,
              const float* __restrict__ m2_w,
              const float* __restrict__ a1_wv, const float* __restrict__ a2_wv,
              const float* __restrict__ a1_wo, const float* __restrict__ a2_wo,
              const float* __restrict__ a1_bv, const float* __restrict__ a1_bo,
              const float* __restrict__ a2_bv, const float* __restrict__ a2_bo,
              const float* __restrict__ tp_b, const float* __restrict__ np_b,
              u16* __restrict__ EMBc, u16* __restrict__ Wbig,
              u16* __restrict__ g_bf, u16* __restrict__ m1_bf, u16* __restrict__ m2_bf,
              u16* __restrict__ a1_wvT, u16* __restrict__ a2_wvT,
              u16* __restrict__ tp_wT, u16* __restrict__ np_wT,
              u16* __restrict__ a1_wo_bf, u16* __restrict__ a2_wo_bf,
              float* __restrict__ w1, float* __restrict__ w2,
              float* __restrict__ zb)
{
    __shared__ float smem[64 * 65];
    const int b = blockIdx.x, tid = threadIdx.x;
    if (b < 4096) {                       // EMBc[row,0:256]=text, [256:512]=num
#pragma unroll
        for (int c = 0; c < 2; ++c) {
            const int q = b * 512 + tid + 256 * c;
            const int e = q * 4, row = e >> 9, col = e & 511;
            const float* src = (col < 256) ? text + (size_t)row * 256 + col
                                           : num + (size_t)row * 256 + (col - 256);
            f32x4 v = *(const f32x4*)src;
            s16x4 o;
            o[0] = (short)f2b(v[0]); o[1] = (short)f2b(v[1]);
            o[2] = (short)f2b(v[2]); o[3] = (short)f2b(v[3]);
            *(s16x4*)(EMBc + e) = o;
        }
    } else if (b < 4352) { cvt_quads(g_w, g_bf, b - 4096, tid); }
    else if (b < 4608) { cvt_quads(m1_w, m1_bf, b - 4352, tid); }
    else if (b < 4672) { cvt_quads(m2_w, m2_bf, b - 4608, tid); }
    else if (b < 4736) {                  // np_w -> Wbig[0:512, 256:512]
#pragma unroll
        for (int c = 0; c < 2; ++c) {
            const int q = (b - 4672) * 512 + tid + 256 * c;
            const int e = q * 4, row = e >> 8, col = e & 255;
            f32x4 v = *(const f32x4*)(np_w + e);
            s16x4 o;
            o[0] = (short)f2b(v[0]); o[1] = (short)f2b(v[1]);
            o[2] = (short)f2b(v[2]); o[3] = (short)f2b(v[3]);
            *(s16x4*)(Wbig + (size_t)row * 512 + 256 + col) = o;
        }
    } else if (b < 4800) {                // tp_w -> Wbig[512:1024, 0:256]
#pragma unroll
        for (int c = 0; c < 2; ++c) {
            const int q = (b - 4736) * 512 + tid + 256 * c;
            const int e = q * 4, row = e >> 8, col = e & 255;
            f32x4 v = *(const f32x4*)(tp_w + e);
            s16x4 o;
            o[0] = (short)f2b(v[0]); o[1] = (short)f2b(v[1]);
            o[2] = (short)f2b(v[2]); o[3] = (short)f2b(v[3]);
            *(s16x4*)(Wbig + (size_t)(512 + row) * 512 + col) = o;
        }
    } else if (b < 4864) {                // a1_wvT = a1_wv.T (bf16)
        const int t = b - 4800;
        transpose_cvt64(a1_wv, 512, a1_wvT, 512, (t >> 3) * 64, (t & 7) * 64, tid, smem);
    } else if (b < 4928) {
        const int t = b - 4864;
        transpose_cvt64(a2_wv, 512, a2_wvT, 512, (t >> 3) * 64, (t & 7) * 64, tid, smem);
    } else if (b < 4960) {                // tp_wT [256x512]
        const int t = b - 4928;
        transpose_cvt64(tp_w, 256, tp_wT, 512, (t >> 2) * 64, (t & 3) * 64, tid, smem);
    } else if (b < 4992) {                // np_wT [256x512]
        const int t = b - 4960;
        transpose_cvt64(np_w, 256, np_wT, 512, (t >> 2) * 64, (t & 3) * 64, tid, smem);
    } else if (b < 5120) { cvt_quads(a1_wo, a1_wo_bf, b - 4992, tid); }
    else if (b < 5248) { cvt_quads(a2_wo, a2_wo_bf, b - 5120, tid); }
    else if (b < 5256) {                  // w1 = a1_wo@a1_bv + a1_bo + np_b
        matvec_rows(a1_wo, a1_bv, a1_bo, np_b, w1, (b - 5248) * 64, tid, smem);
    } else if (b < 5264) {                // w2 = a2_wo@a2_bv + a2_bo + tp_b
        matvec_rows(a2_wo, a2_bv, a2_bo, tp_b, w2, (b - 5256) * 64, tid, smem);
    } else {                              // zb[1024] = 0
        *(f32x4*)&zb[tid * 4] = f32x4{0.f, 0.f, 0.f, 0.f};
    }
}

// bbig[0:512] = M1@tp_b + w1 ; bbig[512:1024] = M2@np_b + w2. M bf16 [512x512].
__global__ __launch_bounds__(256)
void prep_bias(const u16* __restrict__ M1, const u16* __restrict__ M2,
               const float* __restrict__ tp_b, const float* __restrict__ np_b,
               const float* __restrict__ w1, const float* __restrict__ w2,
               float* __restrict__ bbig)
{
    __shared__ float sm[768];
    const int b = blockIdx.x, tid = threadIdx.x;
    const int side = b >> 3, r0 = (b & 7) * 64;
    const u16* M = side ? M2 : M1;
    const float* v = side ? np_b : tp_b;
    const float* w = side ? w2 : w1;
    float* out = bbig + side * 512;
    for (int i = tid; i < 512; i += 256) sm[i] = v[i];
    __syncthreads();
    const int row = r0 + (tid & 63), q = tid >> 6;
    float s = 0.f;
    for (int k = q * 128; k < q * 128 + 128; k += 8) {
        s16x8 m = *(const s16x8*)&M[(size_t)row * 512 + k];
#pragma unroll
        for (int j = 0; j < 8; ++j) s += b2f((u16)m[j]) * sm[k + j];
    }
    sm[512 + tid] = s;
    __syncthreads();
    if (tid < 64)
        out[r0 + tid] = sm[512 + tid] + sm[512 + tid + 64] + sm[512 + tid + 128] +
                        sm[512 + tid + 192] + w[r0 + tid];
}

extern "C" void kernel_launch(void* const* d_in, const int* in_sizes, int n_in,
                              void* d_out, int out_size, void* d_ws, size_t ws_size,
                              hipStream_t stream)
{
    const float* text  = (const float*)d_in[0];
    const float* num   = (const float*)d_in[1];
    const float* tp_w  = (const float*)d_in[2];
    const float* tp_b  = (const float*)d_in[3];
    const float* np_w  = (const float*)d_in[4];
    const float* np_b  = (const float*)d_in[5];
    const float* a1_wv = (const float*)d_in[8];
    const float* a1_bv = (const float*)d_in[11];
    const float* a1_wo = (const float*)d_in[12];
    const float* a1_bo = (const float*)d_in[13];
    const float* a2_wv = (const float*)d_in[16];
    const float* a2_bv = (const float*)d_in[19];
    const float* a2_wo = (const float*)d_in[20];
    const float* a2_bo = (const float*)d_in[21];
    const float* n1_g  = (const float*)d_in[22];
    const float* n1_b  = (const float*)d_in[23];
    const float* n2_g  = (const float*)d_in[24];
    const float* n2_b  = (const float*)d_in[25];
    const float* g_w   = (const float*)d_in[26];
    const float* g_b   = (const float*)d_in[27];
    const float* m1_w  = (const float*)d_in[28];
    const float* m1_b  = (const float*)d_in[29];
    const float* ln1_g = (const float*)d_in[30];
    const float* ln1_b = (const float*)d_in[31];
    const float* m2_w  = (const float*)d_in[32];
    const float* m2_b  = (const float*)d_in[33];
    const float* ln2_g = (const float*)d_in[34];
    const float* ln2_b = (const float*)d_in[35];

    float* outp = (float*)d_out;
    char* ob = (char*)d_out;
    char* ws = (char*)d_ws;
    const size_t KB = 1024, MB = 1048576;

    // d_out scratch: [0,16MB) dead until G3; [16,48MB) dead until G2 (EMBc)
    u16* Wbig    = (u16*)(ob);                       // 1 MB   [1024x512]
    u16* g_bf    = (u16*)(ob + 1 * MB);              // 1 MB   [512x1024]
    u16* m1_bf   = (u16*)(ob + 2 * MB);              // 1 MB   [512x1024]
    u16* a1_wvT  = (u16*)(ob + 3 * MB + 256 * KB);   // 512 KB [512x512]
    u16* a2_wvT  = (u16*)(ob + 3 * MB + 768 * KB);   // 512 KB
    u16* tp_wT   = (u16*)(ob + 4 * MB + 256 * KB);   // 256 KB [256x512]
    u16* np_wT   = (u16*)(ob + 4 * MB + 512 * KB);   // 256 KB
    u16* a1_wo_bf= (u16*)(ob + 4 * MB + 768 * KB);   // 512 KB [512x512]
    u16* a2_wo_bf= (u16*)(ob + 5 * MB + 256 * KB);   // 512 KB
    u16* M1      = (u16*)(ob + 5 * MB + 768 * KB);   // 512 KB [512x512]
    u16* M2      = (u16*)(ob + 6 * MB + 256 * KB);   // 512 KB
    float* w1    = (float*)(ob + 6 * MB + 768 * KB); // 2 KB
    float* w2    = w1 + 512;                         // 2 KB
    float* bbig  = w1 + 1024;                        // 4 KB
    float* zb    = w1 + 2048;                        // 4 KB
    u16* EMBc    = (u16*)(ob + 16 * MB);             // 16 MB [16384x512]
    // ws: X live prep->G2; m2_bf live prep->G3 (kept out of d_out[0,16MB) since
    // fused G3 writes d_out[0,16MB) while reading m2_bf); h live G2->G3.
    u16* X     = (u16*)ws;                           // 32 MB [16384x1024]
    u16* m2_bf = (u16*)(ws + 32 * MB);               // 256 KB [256x512]
    u16* h     = (u16*)(ws + 48 * MB);               // 16 MB [16384x512]

    dim3 blk(256);

    // P1: conversions, transposes, w1/w2, zbias
    prep_cvt<<<5265, blk, 0, stream>>>(text, num, tp_w, np_w, g_w, m1_w, m2_w,
        a1_wv, a2_wv, a1_wo, a2_wo, a1_bv, a1_bo, a2_bv, a2_bo, tp_b, np_b,
        EMBc, Wbig, g_bf, m1_bf, m2_bf, a1_wvT, a2_wvT, tp_wT, np_wT,
        a1_wo_bf, a2_wo_bf, w1, w2, zb);
    // F1: M1 = a1_wo@a1_wv ; M2 = a2_wo@a2_wv   (16-row tiles -> 128 blocks)
    gemm_bt<1, 1><<<dim3(4, 32), blk, 0, stream>>>(a1_wo_bf, a2_wo_bf, a1_wvT, a2_wvT,
        zb, zb, nullptr, nullptr, nullptr, nullptr,
        M1, M2, 512, 512, 2, 512, 512, 0, 0);
    // PB: bbig = [M1@tp_b + w1 | M2@np_b + w2]
    prep_bias<<<16, blk, 0, stream>>>(M1, M2, tp_b, np_b, w1, w2, bbig);
    // F2: Wbig[0:512,0:256] = M1@tp_w ; Wbig[512:,256:] = M2@np_w (64 blocks)
    gemm_bt<1, 1><<<dim3(2, 32), blk, 0, stream>>>(M1, M2, tp_wT, np_wT,
        zb, zb, nullptr, nullptr, nullptr, nullptr,
        Wbig, Wbig + (size_t)512 * 512 + 256, 512, 512, 1, 512, 512, 0, 0);
    // G1+L1: X = LN(EMBc @ Wbig.T + bbig) per 512-col half (n1 | n2), fused
    gemm_bt<2, 4><<<dim3(2, 256), blk, 0, stream>>>(EMBc, EMBc,
        Wbig, Wbig + (size_t)512 * 512, bbig, bbig + 512,
        n1_g, n1_b, n2_g, n2_b,
        X, X + 512, 512, 512, 1, 1024, 1024, 2, 2);
    // G2+L2: gate = sigmoid(comb@g_w.T+g_b) -> d_out f32 ; h = gelu(LN1(comb@m1_w.T+m1_b))
    gemm_bt<2, 4><<<dim3(2, 256), blk, 0, stream>>>(X, X, g_bf, m1_bf, g_b, m1_b,
        nullptr, nullptr, ln1_g, ln1_b,
        outp + (size_t)16384 * 256, h, 1024, 1024, 1, 512, 512, 1, 3);
    // G3+L3: fused = gelu(LN2(h @ m2_w.T + m2_b)) -> d_out f32; attn = 1.0
    gemm_bt<1, 4><<<dim3(1, 256), blk, 0, stream>>>(h, h, m2_bf, m2_bf, m2_b, m2_b,
        ln2_g, ln2_b, ln2_g, ln2_b,
        outp, outp, 512, 512, 1, 256, 256, 4, 4);
}